// Round 1
// baseline (912.143 us; speedup 1.0000x reference)
//
#include <hip/hip_runtime.h>
#include <hip/hip_bf16.h>
#include <math.h>

// Problem constants
#define BB 2
#define LL 512
#define CC 256
#define HH 8
#define DD 32
#define LN_EPS 1e-5f
#define SCALE 0.17677669529663687f   // 1/sqrt(32)

// ---------------------------------------------------------------------------
// K1: qkv = x @ w_qkv^T, scattered into q/k/v laid out [B,H,L,D] (contiguous
// blocks of 262144 floats each, q base passed in).
// M=1024 rows (b,l), N=768 cols, K=256. 64x64 tile, 4x4 micro-tile.
// ---------------------------------------------------------------------------
__global__ __launch_bounds__(256) void k1_qkv(const float* __restrict__ x,
                                              const float* __restrict__ w,
                                              float* __restrict__ qkv_out) {
    __shared__ float xs[16][64];
    __shared__ float wsd[16][64];
    const int row0 = blockIdx.x * 64;
    const int col0 = blockIdx.y * 64;
    const int t  = threadIdx.x;
    const int ry = t >> 4;   // 0..15
    const int cx = t & 15;   // 0..15
    const int lr = t >> 2;   // 0..63 row for staging load
    const int lq = t & 3;    // 0..3  16B chunk
    float acc[4][4] = {};
    for (int k0 = 0; k0 < 256; k0 += 16) {
        float4 xv = *(const float4*)(x + (row0 + lr) * 256 + k0 + 4 * lq);
        float4 wv = *(const float4*)(w + (col0 + lr) * 256 + k0 + 4 * lq);
        xs[4*lq+0][lr] = xv.x; xs[4*lq+1][lr] = xv.y;
        xs[4*lq+2][lr] = xv.z; xs[4*lq+3][lr] = xv.w;
        wsd[4*lq+0][lr] = wv.x; wsd[4*lq+1][lr] = wv.y;
        wsd[4*lq+2][lr] = wv.z; wsd[4*lq+3][lr] = wv.w;
        __syncthreads();
#pragma unroll
        for (int kk = 0; kk < 16; ++kk) {
            float4 a  = *(const float4*)&xs[kk][4*ry];
            float4 bb = *(const float4*)&wsd[kk][4*cx];
            float av[4] = {a.x, a.y, a.z, a.w};
            float bv[4] = {bb.x, bb.y, bb.z, bb.w};
#pragma unroll
            for (int rr = 0; rr < 4; ++rr)
#pragma unroll
                for (int cc = 0; cc < 4; ++cc)
                    acc[rr][cc] = fmaf(av[rr], bv[cc], acc[rr][cc]);
        }
        __syncthreads();
    }
#pragma unroll
    for (int rr = 0; rr < 4; ++rr) {
        const int row = row0 + 4*ry + rr;
        const int b = row >> 9, l = row & 511;
#pragma unroll
        for (int cc = 0; cc < 4; ++cc) {
            const int o = col0 + 4*cx + cc;
            const int three = o >> 8;
            const int hh = (o >> 5) & 7;
            const int dd = o & 31;
            qkv_out[three * 262144 + ((b*8 + hh)*512 + l)*32 + dd] = acc[rr][cc];
        }
    }
}

// ---------------------------------------------------------------------------
// K2: rel[b,i,j,h] = LN_h( gelu( relative_pos[b,i,j,:] . w_rel[h,:] + b_rel[h] ) )
// One wave per (b,i,j) position. Lane loads float4 of the 256-dim row.
// Partial dots for all 8 heads, butterfly over lane bits 3..5, then lane
// group h = lane>>3 owns head h (replicated x8 over bits 0..2).
// ---------------------------------------------------------------------------
__global__ __launch_bounds__(256) void k2_rel(const float* __restrict__ rp,
                                              const float* __restrict__ wr,
                                              const float* __restrict__ br,
                                              const float* __restrict__ gam_p,
                                              const float* __restrict__ bet_p,
                                              float* __restrict__ rel) {
    const int lane = threadIdx.x & 63;
    const int wid  = blockIdx.x * 4 + (threadIdx.x >> 6);  // 0..4095
    float4 wv[8];
#pragma unroll
    for (int h = 0; h < 8; ++h)
        wv[h] = *(const float4*)(wr + h * 256 + 4 * lane);
    const int s = lane >> 3;       // head owned by this lane group
    const float bre = br[s];
    const float gam = gam_p[s];
    const float bet = bet_p[s];

    for (int it = 0; it < 128; ++it) {
        const long pos = (long)wid + (long)it * 4096;   // 0..524287
        float4 a = *(const float4*)(rp + pos * 256 + 4 * lane);
        float p[8];
#pragma unroll
        for (int h = 0; h < 8; ++h) {
            float acc = a.x * wv[h].x;
            acc = fmaf(a.y, wv[h].y, acc);
            acc = fmaf(a.z, wv[h].z, acc);
            acc = fmaf(a.w, wv[h].w, acc);
            p[h] = acc;
        }
        // reduce over lane bits 3,4,5: each lane now holds S[h][c=lane&7]
#pragma unroll
        for (int h = 0; h < 8; ++h) {
            p[h] += __shfl_xor(p[h], 8);
            p[h] += __shfl_xor(p[h], 16);
            p[h] += __shfl_xor(p[h], 32);
        }
        // select register h = lane>>3 (binary cndmask tree)
        float a0 = (s & 1) ? p[1] : p[0];
        float a1 = (s & 1) ? p[3] : p[2];
        float a2 = (s & 1) ? p[5] : p[4];
        float a3 = (s & 1) ? p[7] : p[6];
        float b0 = (s & 2) ? a1 : a0;
        float b1 = (s & 2) ? a3 : a2;
        float rv = (s & 4) ? b1 : b0;
        // sum over chunks c (bits 0,1,2) -> full dot for head s
        rv += __shfl_xor(rv, 1);
        rv += __shfl_xor(rv, 2);
        rv += __shfl_xor(rv, 4);
        rv += bre;
        // exact GELU
        float g = 0.5f * rv * (1.0f + erff(rv * 0.70710678118654752f));
        // LayerNorm across heads (across lane bits 3,4,5)
        float sg = g, sg2 = g * g;
        sg  += __shfl_xor(sg, 8);   sg2 += __shfl_xor(sg2, 8);
        sg  += __shfl_xor(sg, 16);  sg2 += __shfl_xor(sg2, 16);
        sg  += __shfl_xor(sg, 32);  sg2 += __shfl_xor(sg2, 32);
        const float mu  = sg * 0.125f;
        const float var = fmaf(sg2, 0.125f, -mu * mu);
        const float o = fmaf((g - mu) * rsqrtf(var + LN_EPS), gam, bet);
        // gather: lane w (w<8) takes head w's value from lane 8w
        const float ov = __shfl(o, (lane & 7) * 8);
        if (lane < 8) rel[pos * 8 + lane] = ov;
    }
}

// ---------------------------------------------------------------------------
// K3: attention. One wave per (b,h,i) row.
// scores j-parallel (8 j per lane), softmax via butterflies, p -> LDS,
// PV d-parallel (lane = (d, j-half)) with coalesced v reads.
// ---------------------------------------------------------------------------
__global__ __launch_bounds__(256) void k3_attn(const float* __restrict__ qg,
                                               const float* __restrict__ kg,
                                               const float* __restrict__ vg,
                                               const float* __restrict__ rel,
                                               float* __restrict__ outg) {
    __shared__ float p_lds[4][512];
    const int lane = threadIdx.x & 63;
    const int wid  = threadIdx.x >> 6;
    const int row  = blockIdx.x * 4 + wid;       // 0..8191
    const int b = row >> 12;
    const int h = (row >> 9) & 7;
    const int i = row & 511;

    const float* qp = qg + ((b*8 + h)*512 + i) * 32;
    float4 qv[8];
#pragma unroll
    for (int dd = 0; dd < 8; ++dd)
        qv[dd] = *(const float4*)(qp + 4 * dd);

    const float* kp0  = kg + (long)((b*8 + h)*512) * 32;
    const float* relp = rel + ((long)(b*512 + i) * 512) * 8 + h;

    float sc[8];
#pragma unroll
    for (int t = 0; t < 8; ++t) {
        const int j = lane + 64 * t;
        const float* kp = kp0 + j * 32;
        float acc = 0.0f;
#pragma unroll
        for (int dd = 0; dd < 8; ++dd) {
            float4 k4 = *(const float4*)(kp + 4 * dd);
            acc = fmaf(qv[dd].x, k4.x, acc);
            acc = fmaf(qv[dd].y, k4.y, acc);
            acc = fmaf(qv[dd].z, k4.z, acc);
            acc = fmaf(qv[dd].w, k4.w, acc);
        }
        const float rl = relp[(long)j * 8];
        sc[t] = (acc + rl) * SCALE;
    }
    // row max
    float m = sc[0];
#pragma unroll
    for (int t = 1; t < 8; ++t) m = fmaxf(m, sc[t]);
    m = fmaxf(m, __shfl_xor(m, 1));
    m = fmaxf(m, __shfl_xor(m, 2));
    m = fmaxf(m, __shfl_xor(m, 4));
    m = fmaxf(m, __shfl_xor(m, 8));
    m = fmaxf(m, __shfl_xor(m, 16));
    m = fmaxf(m, __shfl_xor(m, 32));
    // exp + sum
    float sum = 0.0f;
#pragma unroll
    for (int t = 0; t < 8; ++t) { sc[t] = __expf(sc[t] - m); sum += sc[t]; }
    sum += __shfl_xor(sum, 1);
    sum += __shfl_xor(sum, 2);
    sum += __shfl_xor(sum, 4);
    sum += __shfl_xor(sum, 8);
    sum += __shfl_xor(sum, 16);
    sum += __shfl_xor(sum, 32);
    const float inv = 1.0f / sum;
#pragma unroll
    for (int t = 0; t < 8; ++t)
        p_lds[wid][lane + 64 * t] = sc[t] * inv;
    __syncthreads();

    // PV: lane = (d = lane&31, half = lane>>5), each half sums 256 j's
    const int d = lane & 31;
    const int half = lane >> 5;
    const float* vp = vg + (long)((b*8 + h)*512) * 32 + d;
    const float* pw = &p_lds[wid][half * 256];
    float acc = 0.0f;
#pragma unroll 4
    for (int jj = 0; jj < 256; ++jj)
        acc = fmaf(pw[jj], vp[(half * 256 + jj) * 32], acc);
    acc += __shfl_xor(acc, 32);
    if (lane < 32)
        outg[(b*512 + i) * 256 + h * 32 + d] = acc;
}

// ---------------------------------------------------------------------------
// K4: out = attn @ w_proj^T + b_proj.  M=1024, N=256, K=256. Same tiling as K1.
// ---------------------------------------------------------------------------
__global__ __launch_bounds__(256) void k4_proj(const float* __restrict__ a_in,
                                               const float* __restrict__ w,
                                               const float* __restrict__ bp,
                                               float* __restrict__ outg) {
    __shared__ float xs[16][64];
    __shared__ float wsd[16][64];
    const int row0 = blockIdx.x * 64;
    const int col0 = blockIdx.y * 64;
    const int t  = threadIdx.x;
    const int ry = t >> 4;
    const int cx = t & 15;
    const int lr = t >> 2;
    const int lq = t & 3;
    float acc[4][4] = {};
    for (int k0 = 0; k0 < 256; k0 += 16) {
        float4 xv = *(const float4*)(a_in + (row0 + lr) * 256 + k0 + 4 * lq);
        float4 wv = *(const float4*)(w + (col0 + lr) * 256 + k0 + 4 * lq);
        xs[4*lq+0][lr] = xv.x; xs[4*lq+1][lr] = xv.y;
        xs[4*lq+2][lr] = xv.z; xs[4*lq+3][lr] = xv.w;
        wsd[4*lq+0][lr] = wv.x; wsd[4*lq+1][lr] = wv.y;
        wsd[4*lq+2][lr] = wv.z; wsd[4*lq+3][lr] = wv.w;
        __syncthreads();
#pragma unroll
        for (int kk = 0; kk < 16; ++kk) {
            float4 a  = *(const float4*)&xs[kk][4*ry];
            float4 bb = *(const float4*)&wsd[kk][4*cx];
            float av[4] = {a.x, a.y, a.z, a.w};
            float bv[4] = {bb.x, bb.y, bb.z, bb.w};
#pragma unroll
            for (int rr = 0; rr < 4; ++rr)
#pragma unroll
                for (int cc = 0; cc < 4; ++cc)
                    acc[rr][cc] = fmaf(av[rr], bv[cc], acc[rr][cc]);
        }
        __syncthreads();
    }
#pragma unroll
    for (int rr = 0; rr < 4; ++rr) {
        const int row = row0 + 4*ry + rr;
#pragma unroll
        for (int cc = 0; cc < 4; ++cc) {
            const int col = col0 + 4*cx + cc;
            outg[row * 256 + col] = acc[rr][cc] + bp[col];
        }
    }
}

// ---------------------------------------------------------------------------
extern "C" void kernel_launch(void* const* d_in, const int* in_sizes, int n_in,
                              void* d_out, int out_size, void* d_ws, size_t ws_size,
                              hipStream_t stream) {
    const float* x      = (const float*)d_in[0];
    const float* rp     = (const float*)d_in[1];
    const float* w_qkv  = (const float*)d_in[2];
    const float* w_rel  = (const float*)d_in[3];
    const float* b_rel  = (const float*)d_in[4];
    const float* gamma  = (const float*)d_in[5];
    const float* beta   = (const float*)d_in[6];
    const float* w_proj = (const float*)d_in[7];
    const float* b_proj = (const float*)d_in[8];
    float* out = (float*)d_out;
    float* ws  = (float*)d_ws;

    // workspace layout (floats):
    // q: [0, 262144)   k: [262144, 524288)   v: [524288, 786432)
    // rel [B,L,L,H]: [786432, 4980736)       attn [B,L,C]: [4980736, 5242880)
    float* q    = ws;
    float* kk   = ws + 262144;
    float* vv   = ws + 524288;
    float* rel  = ws + 786432;
    float* attn = ws + 786432 + 4194304;

    k1_qkv<<<dim3(16, 12), 256, 0, stream>>>(x, w_qkv, q);
    k2_rel<<<1024, 256, 0, stream>>>(rp, w_rel, b_rel, gamma, beta, rel);
    k3_attn<<<2048, 256, 0, stream>>>(q, kk, vv, rel, attn);
    k4_proj<<<dim3(16, 4), 256, 0, stream>>>(attn, w_proj, b_proj, out);
}

// Round 2
// 826.899 us; speedup vs baseline: 1.1031x; 1.1031x over previous
//
#include <hip/hip_runtime.h>
#include <hip/hip_bf16.h>
#include <math.h>

// Problem constants
#define BB 2
#define LL 512
#define CC 256
#define HH 8
#define DD 32
#define LN_EPS 1e-5f
#define SCALE 0.17677669529663687f   // 1/sqrt(32)
#define RSQRT2 0.70710678118654752f

// ---------------------------------------------------------------------------
// K1: qkv = x @ w_qkv^T, scattered into q/k/v laid out [B,H,L,D].
// M=1024 rows (b,l), N=768 cols, K=256. 64x64 tile, 4x4 micro-tile.
// ---------------------------------------------------------------------------
__global__ __launch_bounds__(256) void k1_qkv(const float* __restrict__ x,
                                              const float* __restrict__ w,
                                              float* __restrict__ qkv_out) {
    __shared__ float xs[16][64];
    __shared__ float wsd[16][64];
    const int row0 = blockIdx.x * 64;
    const int col0 = blockIdx.y * 64;
    const int t  = threadIdx.x;
    const int ry = t >> 4;   // 0..15
    const int cx = t & 15;   // 0..15
    const int lr = t >> 2;   // 0..63 row for staging load
    const int lq = t & 3;    // 0..3  16B chunk
    float acc[4][4] = {};
    for (int k0 = 0; k0 < 256; k0 += 16) {
        float4 xv = *(const float4*)(x + (row0 + lr) * 256 + k0 + 4 * lq);
        float4 wv = *(const float4*)(w + (col0 + lr) * 256 + k0 + 4 * lq);
        xs[4*lq+0][lr] = xv.x; xs[4*lq+1][lr] = xv.y;
        xs[4*lq+2][lr] = xv.z; xs[4*lq+3][lr] = xv.w;
        wsd[4*lq+0][lr] = wv.x; wsd[4*lq+1][lr] = wv.y;
        wsd[4*lq+2][lr] = wv.z; wsd[4*lq+3][lr] = wv.w;
        __syncthreads();
#pragma unroll
        for (int kk = 0; kk < 16; ++kk) {
            float4 a  = *(const float4*)&xs[kk][4*ry];
            float4 bb = *(const float4*)&wsd[kk][4*cx];
            float av[4] = {a.x, a.y, a.z, a.w};
            float bv[4] = {bb.x, bb.y, bb.z, bb.w};
#pragma unroll
            for (int rr = 0; rr < 4; ++rr)
#pragma unroll
                for (int cc = 0; cc < 4; ++cc)
                    acc[rr][cc] = fmaf(av[rr], bv[cc], acc[rr][cc]);
        }
        __syncthreads();
    }
#pragma unroll
    for (int rr = 0; rr < 4; ++rr) {
        const int row = row0 + 4*ry + rr;
        const int b = row >> 9, l = row & 511;
#pragma unroll
        for (int cc = 0; cc < 4; ++cc) {
            const int o = col0 + 4*cx + cc;
            const int three = o >> 8;
            const int hh = (o >> 5) & 7;
            const int dd = o & 31;
            qkv_out[three * 262144 + ((b*8 + hh)*512 + l)*32 + dd] = acc[rr][cc];
        }
    }
}

// ---------------------------------------------------------------------------
// K2 (redesigned): rel_t[b,h,i,j] = LN_h( gelu( rp[b,i,j,:] . w_rel[h,:] + b_rel[h] ) )
// Block = (b, i, 32-wide j tile). Stage the 32x256 rp tile (contiguous 32 KB)
// into LDS with row stride 260 (pad 4 -> conflict-free reads: rp banks
// 4(j+c)%32, w banks 4(h+c)%32, broadcast over the other index). Thread owns
// one (j,h) output: 64xfloat4 FMA dot, one erf, LN via 3 octet shuffles.
// Output written TRANSPOSED [B,H,L,L] via small LDS transpose so K3 reads
// rel coalesced.
// ---------------------------------------------------------------------------
__global__ __launch_bounds__(256) void k2_rel(const float* __restrict__ rp,
                                              const float* __restrict__ wr,
                                              const float* __restrict__ br,
                                              const float* __restrict__ gam_p,
                                              const float* __restrict__ bet_p,
                                              float* __restrict__ rel_t) {
    __shared__ float rps[32 * 260];   // rp tile, padded rows
    __shared__ float wls[8 * 260];    // w_rel, padded rows
    __shared__ float st[8][33];       // output transpose buffer
    const int t   = threadIdx.x;
    const int blk = blockIdx.x;       // 0..16383
    const int jt  = blk & 15;
    const int i   = (blk >> 4) & 511;
    const int b   = blk >> 13;
    const int j0  = jt << 5;

    // stage w_rel (8x256 = 512 float4, 2 per thread), padded stride 260
    {
        const float4* ws4 = (const float4*)wr;
        int idx = t;
        int hh = idx >> 6, c4 = idx & 63;
        *(float4*)&wls[hh * 260 + 4 * c4] = ws4[idx];
        idx = t + 256;
        hh = idx >> 6; c4 = idx & 63;
        *(float4*)&wls[hh * 260 + 4 * c4] = ws4[idx];
    }
    // stage rp tile: row jr = t>>3, 8 threads/row, each 8 float4 strided
    const int jr = t >> 3;            // 0..31
    const int u  = t & 7;             // 0..7
    const float4* rsrc = (const float4*)(rp + (((long)(b * 512 + i) * 512) + j0 + jr) * 256);
#pragma unroll
    for (int c = 0; c < 8; ++c)
        *(float4*)&rps[jr * 260 + 4 * (u + 8 * c)] = rsrc[u + 8 * c];
    __syncthreads();

    // compute: thread owns (j = jr, h = t&7)
    const int h = t & 7;
    const float* ar   = &rps[jr * 260];
    const float* wrow = &wls[h * 260];
    float4 acc = {0.f, 0.f, 0.f, 0.f};
#pragma unroll 8
    for (int c4 = 0; c4 < 64; ++c4) {
        float4 a = *(const float4*)&ar[4 * c4];
        float4 w = *(const float4*)&wrow[4 * c4];
        acc.x = fmaf(a.x, w.x, acc.x);
        acc.y = fmaf(a.y, w.y, acc.y);
        acc.z = fmaf(a.z, w.z, acc.z);
        acc.w = fmaf(a.w, w.w, acc.w);
    }
    float r = ((acc.x + acc.y) + (acc.z + acc.w)) + br[h];
    // exact GELU
    float g = 0.5f * r * (1.0f + erff(r * RSQRT2));
    // LayerNorm across h = lane bits 0..2 (threads of one octet share jr)
    float sg = g, sg2 = g * g;
    sg += __shfl_xor(sg, 1); sg2 += __shfl_xor(sg2, 1);
    sg += __shfl_xor(sg, 2); sg2 += __shfl_xor(sg2, 2);
    sg += __shfl_xor(sg, 4); sg2 += __shfl_xor(sg2, 4);
    const float mu  = sg * 0.125f;
    const float var = fmaf(sg2, 0.125f, -mu * mu);
    const float o = fmaf((g - mu) * rsqrtf(var + LN_EPS), gam_p[h], bet_p[h]);
    st[h][jr] = o;
    __syncthreads();
    // coalesced transposed store: 32-lane groups write 128B runs of j
    const int h2 = t >> 5, j2 = t & 31;
    rel_t[(((long)(b * 8 + h2) * 512) + i) * 512 + j0 + j2] = st[h2][j2];
}

// ---------------------------------------------------------------------------
// K3: attention. One wave per (b,h,i) row. rel is now [B,H,L,L] -> coalesced.
// ---------------------------------------------------------------------------
__global__ __launch_bounds__(256) void k3_attn(const float* __restrict__ qg,
                                               const float* __restrict__ kg,
                                               const float* __restrict__ vg,
                                               const float* __restrict__ rel_t,
                                               float* __restrict__ outg) {
    __shared__ float p_lds[4][512];
    const int lane = threadIdx.x & 63;
    const int wid  = threadIdx.x >> 6;
    const int row  = blockIdx.x * 4 + wid;       // 0..8191
    const int b = row >> 12;
    const int h = (row >> 9) & 7;
    const int i = row & 511;

    const float* qp = qg + ((b*8 + h)*512 + i) * 32;
    float4 qv[8];
#pragma unroll
    for (int dd = 0; dd < 8; ++dd)
        qv[dd] = *(const float4*)(qp + 4 * dd);

    const float* kp0  = kg + (long)((b*8 + h)*512) * 32;
    const float* relp = rel_t + (((long)(b*8 + h)*512) + i) * 512;

    float sc[8];
#pragma unroll
    for (int tt = 0; tt < 8; ++tt) {
        const int j = lane + 64 * tt;
        const float* kp = kp0 + j * 32;
        float acc = 0.0f;
#pragma unroll
        for (int dd = 0; dd < 8; ++dd) {
            float4 k4 = *(const float4*)(kp + 4 * dd);
            acc = fmaf(qv[dd].x, k4.x, acc);
            acc = fmaf(qv[dd].y, k4.y, acc);
            acc = fmaf(qv[dd].z, k4.z, acc);
            acc = fmaf(qv[dd].w, k4.w, acc);
        }
        sc[tt] = (acc + relp[j]) * SCALE;
    }
    // row max
    float m = sc[0];
#pragma unroll
    for (int tt = 1; tt < 8; ++tt) m = fmaxf(m, sc[tt]);
    m = fmaxf(m, __shfl_xor(m, 1));
    m = fmaxf(m, __shfl_xor(m, 2));
    m = fmaxf(m, __shfl_xor(m, 4));
    m = fmaxf(m, __shfl_xor(m, 8));
    m = fmaxf(m, __shfl_xor(m, 16));
    m = fmaxf(m, __shfl_xor(m, 32));
    // exp + sum
    float sum = 0.0f;
#pragma unroll
    for (int tt = 0; tt < 8; ++tt) { sc[tt] = __expf(sc[tt] - m); sum += sc[tt]; }
    sum += __shfl_xor(sum, 1);
    sum += __shfl_xor(sum, 2);
    sum += __shfl_xor(sum, 4);
    sum += __shfl_xor(sum, 8);
    sum += __shfl_xor(sum, 16);
    sum += __shfl_xor(sum, 32);
    const float inv = 1.0f / sum;
#pragma unroll
    for (int tt = 0; tt < 8; ++tt)
        p_lds[wid][lane + 64 * tt] = sc[tt] * inv;
    __syncthreads();

    // PV: lane = (d = lane&31, half = lane>>5); 4 independent acc chains
    const int d = lane & 31;
    const int half = lane >> 5;
    const float* vp = vg + (long)((b*8 + h)*512) * 32 + (half * 256) * 32 + d;
    const float* pw = &p_lds[wid][half * 256];
    float a0 = 0.f, a1 = 0.f, a2 = 0.f, a3 = 0.f;
#pragma unroll 4
    for (int jj = 0; jj < 256; jj += 4) {
        a0 = fmaf(pw[jj + 0], vp[(jj + 0) * 32], a0);
        a1 = fmaf(pw[jj + 1], vp[(jj + 1) * 32], a1);
        a2 = fmaf(pw[jj + 2], vp[(jj + 2) * 32], a2);
        a3 = fmaf(pw[jj + 3], vp[(jj + 3) * 32], a3);
    }
    float acc = (a0 + a1) + (a2 + a3);
    acc += __shfl_xor(acc, 32);
    if (lane < 32)
        outg[(b*512 + i) * 256 + h * 32 + d] = acc;
}

// ---------------------------------------------------------------------------
// K4: out = attn @ w_proj^T + b_proj.  M=1024, N=256, K=256.
// ---------------------------------------------------------------------------
__global__ __launch_bounds__(256) void k4_proj(const float* __restrict__ a_in,
                                               const float* __restrict__ w,
                                               const float* __restrict__ bp,
                                               float* __restrict__ outg) {
    __shared__ float xs[16][64];
    __shared__ float wsd[16][64];
    const int row0 = blockIdx.x * 64;
    const int col0 = blockIdx.y * 64;
    const int t  = threadIdx.x;
    const int ry = t >> 4;
    const int cx = t & 15;
    const int lr = t >> 2;
    const int lq = t & 3;
    float acc[4][4] = {};
    for (int k0 = 0; k0 < 256; k0 += 16) {
        float4 xv = *(const float4*)(a_in + (row0 + lr) * 256 + k0 + 4 * lq);
        float4 wv = *(const float4*)(w + (col0 + lr) * 256 + k0 + 4 * lq);
        xs[4*lq+0][lr] = xv.x; xs[4*lq+1][lr] = xv.y;
        xs[4*lq+2][lr] = xv.z; xs[4*lq+3][lr] = xv.w;
        wsd[4*lq+0][lr] = wv.x; wsd[4*lq+1][lr] = wv.y;
        wsd[4*lq+2][lr] = wv.z; wsd[4*lq+3][lr] = wv.w;
        __syncthreads();
#pragma unroll
        for (int kk = 0; kk < 16; ++kk) {
            float4 a  = *(const float4*)&xs[kk][4*ry];
            float4 bb = *(const float4*)&wsd[kk][4*cx];
            float av[4] = {a.x, a.y, a.z, a.w};
            float bv[4] = {bb.x, bb.y, bb.z, bb.w};
#pragma unroll
            for (int rr = 0; rr < 4; ++rr)
#pragma unroll
                for (int cc = 0; cc < 4; ++cc)
                    acc[rr][cc] = fmaf(av[rr], bv[cc], acc[rr][cc]);
        }
        __syncthreads();
    }
#pragma unroll
    for (int rr = 0; rr < 4; ++rr) {
        const int row = row0 + 4*ry + rr;
#pragma unroll
        for (int cc = 0; cc < 4; ++cc) {
            const int col = col0 + 4*cx + cc;
            outg[row * 256 + col] = acc[rr][cc] + bp[col];
        }
    }
}

// ---------------------------------------------------------------------------
extern "C" void kernel_launch(void* const* d_in, const int* in_sizes, int n_in,
                              void* d_out, int out_size, void* d_ws, size_t ws_size,
                              hipStream_t stream) {
    const float* x      = (const float*)d_in[0];
    const float* rp     = (const float*)d_in[1];
    const float* w_qkv  = (const float*)d_in[2];
    const float* w_rel  = (const float*)d_in[3];
    const float* b_rel  = (const float*)d_in[4];
    const float* gamma  = (const float*)d_in[5];
    const float* beta   = (const float*)d_in[6];
    const float* w_proj = (const float*)d_in[7];
    const float* b_proj = (const float*)d_in[8];
    float* out = (float*)d_out;
    float* ws  = (float*)d_ws;

    // workspace layout (floats):
    // q: [0, 262144)   k: [262144, 524288)   v: [524288, 786432)
    // rel_t [B,H,L,L]: [786432, 4980736)     attn [B,L,C]: [4980736, 5242880)
    float* q     = ws;
    float* kk    = ws + 262144;
    float* vv    = ws + 524288;
    float* rel_t = ws + 786432;
    float* attn  = ws + 786432 + 4194304;

    k1_qkv<<<dim3(16, 12), 256, 0, stream>>>(x, w_qkv, q);
    k2_rel<<<16384, 256, 0, stream>>>(rp, w_rel, b_rel, gamma, beta, rel_t);
    k3_attn<<<2048, 256, 0, stream>>>(q, kk, vv, rel_t, attn);
    k4_proj<<<dim3(16, 4), 256, 0, stream>>>(attn, w_proj, b_proj, out);
}